// Round 14
// baseline (158.999 us; speedup 1.0000x reference)
//
#include <hip/hip_runtime.h>
#include <cstdint>

// XLA emits separate mul/add; contraction off by default. Hot paths use
// explicit fmaf()/hw-transcendentals — measured-safe across 11 rounds
// (absmax pinned at 3.36e7 vs threshold 4.76e34 for r8-r13's variants).
#pragma clang fp contract(off)

#define TSAVES 49
#define SPSAVE 100
#define NB 8192
#define TRAJ 32                    // trajectories per block
#define GENW 14                    // noise-generator waves per block
#define NITER 51                   // 49 groups + 2 pipeline-drain iters

typedef float f32x4 __attribute__((ext_vector_type(4)));

__device__ __forceinline__ uint32_t rotl32(uint32_t v, int d) {
  return __builtin_rotateleft32(v, (uint32_t)d);
}

// JAX threefry2x32, 20 rounds.
__device__ __forceinline__ void tf2x32(uint32_t k0, uint32_t k1,
                                       uint32_t x0, uint32_t x1,
                                       uint32_t& o0, uint32_t& o1) {
  uint32_t ks2 = k0 ^ k1 ^ 0x1BD11BDAu;
#define TF_ROUND(r) { x0 += x1; x1 = rotl32(x1, r); x1 ^= x0; }
  x0 += k0; x1 += k1;
  TF_ROUND(13) TF_ROUND(15) TF_ROUND(26) TF_ROUND(6)
  x0 += k1; x1 += ks2 + 1u;
  TF_ROUND(17) TF_ROUND(29) TF_ROUND(16) TF_ROUND(24)
  x0 += ks2; x1 += k0 + 2u;
  TF_ROUND(13) TF_ROUND(15) TF_ROUND(26) TF_ROUND(6)
  x0 += k0; x1 += k1 + 3u;
  TF_ROUND(17) TF_ROUND(29) TF_ROUND(16) TF_ROUND(24)
  x0 += k1; x1 += ks2 + 4u;
  TF_ROUND(13) TF_ROUND(15) TF_ROUND(26) TF_ROUND(6)
  x0 += ks2; x1 += k0 + 5u;
#undef TF_ROUND
  o0 = x0; o1 = x1;
}

// jax.random.split(key(seed)), jax_threefry_partitionable=True (fold-like).
__device__ __forceinline__ void derive_keys(int seed, uint32_t& kn0, uint32_t& kn1,
                                            uint32_t& ku0, uint32_t& ku1) {
  uint64_t sv = (uint64_t)(int64_t)seed;
  uint32_t k0 = (uint32_t)(sv >> 32);
  uint32_t k1 = (uint32_t)(sv & 0xffffffffULL);
  tf2x32(k0, k1, 0u, 0u, kn0, kn1);  // keys[0] = k_noise
  tf2x32(k0, k1, 0u, 1u, ku0, ku1);  // keys[1] = k_u
}

// partitionable random_bits(32): counter = (hi=0, lo=n); bits = y0 ^ y1.
__device__ __forceinline__ uint32_t rand_bits32(uint32_t k0, uint32_t k1, uint32_t n) {
  uint32_t y0, y1;
  tf2x32(k0, k1, 0u, n, y0, y1);
  return y0 ^ y1;
}

// bits -> erfinv-core p*u (XLA ErfInv32/Giles). Caller multiplies by
// cpv = (0.1*sqrt(2))*pvol — validated bit-compatible since r8.
__device__ __forceinline__ float bits_to_eu(uint32_t bits) {
#pragma clang fp contract(fast)
  float u01 = __uint_as_float((bits >> 9) | 0x3f800000u) - 1.0f;
  float u = u01 * 2.0f + (-0.99999994f);
  u = fmaxf(-0.99999994f, u);
  float omu2 = 1.0f - u * u;                       // fma(-u,u,1)
  float w = -(__builtin_amdgcn_logf(omu2) * 0.6931472f);  // v_log (log2) * ln2
  float p;
  if (w < 5.0f) {
    float z = w - 2.5f;
    p = 2.81022636e-08f;
    p = 3.43273939e-07f + p * z;
    p = -3.5233877e-06f + p * z;
    p = -4.39150654e-06f + p * z;
    p = 0.00021858087f + p * z;
    p = -0.00125372503f + p * z;
    p = -0.00417768164f + p * z;
    p = 0.246640727f + p * z;
    p = 1.50140941f + p * z;
  } else {
    float z = __builtin_amdgcn_sqrtf(w) - 3.0f;
    p = -0.000200214257f;
    p = 0.000100950558f + p * z;
    p = 0.00134934322f + p * z;
    p = -0.00367342844f + p * z;
    p = 0.00573950773f + p * z;
    p = -0.0076224613f + p * z;
    p = 0.00943887047f + p * z;
    p = 1.00167406f + p * z;
    p = 2.83297682f + p * z;
  }
  return p * u;
}

__device__ __forceinline__ float clip_param(float x) {
  return fminf(0.99999988f, fmaxf(1e-07f, x));
}

// Fused: 256 blocks x 16 waves. Waves 0..13 generate noise into LDS (no HBM
// noise buffer); wave 14 runs the serial r0 chain; wave 15 runs s,i +
// summarize. Round-14 fix: sim waves (r0/si) at s_setprio(1) — round-13
// showed the serial chain ran 2.2x slower fused than isolated (7600 vs 3400
// cy/group): issue-arbitration interference from co-resident gen waves.
// Priority lets the chain issue the cycle its dep resolves; gen (875 cy of
// work per SIMD per ~3400 cy group) absorbs the leftover slots for free.
__global__ __launch_bounds__(1024) void fused_kernel(const float* __restrict__ cond,
                                                     const int* __restrict__ seedp,
                                                     float* __restrict__ out) {
  __shared__ f32x4 nbuf[2][25][TRAJ];   // [slot][chunk][traj]: 4 steps/chunk, 25.6 KiB
  __shared__ f32x4 rbuf[2][25][TRAJ];   // exiting-r0, same layout, 25.6 KiB
  const int tid = threadIdx.x;
  const int lane = tid & 63;
  const int wv = tid >> 6;
  const int bbase = blockIdx.x * TRAJ;
  const int tr = lane & 31;
  const int h = lane >> 5;              // gen: e-parity selector
  const int b = bbase + tr;

  if (wv >= GENW) __builtin_amdgcn_s_setprio(1);  // sim waves win arbitration

  uint32_t kn0, kn1, ku0, ku1;
  derive_keys(seedp[0], kn0, kn1, ku0, ku1);

  // Per-trajectory params (each role uses what it needs).
  float pinf = clip_param(cond[b * 4 + 0]);
  float prec = clip_param(cond[b * 4 + 1]);
  float pmr  = clip_param(cond[b * 4 + 2]);
  float pvol = clip_param(cond[b * 4 + 3]);
  const float r0m  = pinf / prec;
  const float dtmr = 0.01f * pmr;
  const float c4 = 1.0f - dtmr;
  const float a4 = dtmr * r0m;
  const float c2 = 0.01f * prec;
  const float c3 = 1.0f - c2;
  const float c3p4 = (c3 * c3) * (c3 * c3);
  const float cpv = 0.14142136f * pvol;     // 0.1*sqrt(2) folded (r8+)

  // role state (lanes 32-63 of sim waves duplicate lanes 0-31: same tr, same
  // values — deterministic; duplicate same-value LDS/global writes are benign)
  float r0 = r0m;                           // r0-wave carry
  float s = 0.99f, i = 0.01f, r0in = r0m;   // si-wave carry
  float best = -1.0f; int bi = 0;
  float plg = 0.0f, sd = 0.0f, sd2 = 0.0f;

  for (int g = 0; g < NITER; ++g) {
    if (wv < GENW) {
      // 50 chunk-halves (c, hh); wave w takes ids w, w+14, w+28, w+42.
      if (g <= 48) {
        const uint32_t nbase = (uint32_t)(g * SPSAVE) * (uint32_t)NB + (uint32_t)b;
        float* nb = (float*)&nbuf[g & 1][0][0];
#pragma unroll
        for (int k = 0; k < 4; ++k) {
          const int id = wv + GENW * k;
          if (id < 50) {
            const int c = id >> 1;
            const int e = ((id & 1) << 1) | h;
            uint32_t n = nbase + (uint32_t)(4 * c + e) * (uint32_t)NB;
            float eu = bits_to_eu(rand_bits32(kn0, kn1, n));
            nb[(c * 32 + tr) * 4 + e] = eu * cpv;
          }
        }
      }
    } else if (wv == GENW) {
      // r0 chain for group g-1: b128 read/write per 4 steps, prefetched.
      if (g >= 1 && g <= 49) {
        const int src = (g - 1) & 1;
        f32x4 vd = nbuf[src][0][tr];
#pragma unroll
        for (int c = 0; c < 25; ++c) {
          f32x4 vdn = (c < 24) ? nbuf[src][c + 1][tr] : vd;  // prefetch next
          f32x4 w;
#pragma unroll
          for (int e = 0; e < 4; ++e) {
            float sq  = __builtin_amdgcn_sqrtf(fabsf(r0));
            float r0h = fmaf(c4, r0, a4);
            r0 = fmaf(sq, vd[e], r0h);
            w[e] = r0;                       // exiting r0
          }
          rbuf[src][c][tr] = w;
          vd = vdn;
        }
      }
    } else {
      // s,i + summarize for group g-2 (rbuf[(g-2)&1] == rbuf[g&1]).
      if (g >= 2) {
        const int t = g - 2;
        const int src = g & 1;
        f32x4 rv = rbuf[src][0][tr];
#pragma unroll
        for (int c = 0; c < 25; ++c) {
          f32x4 rvn = (c < 24) ? rbuf[src][c + 1][tr] : rv;  // prefetch next
          float rs0 = r0in * s;  s = fmaf(-c2, rs0, s);
          float rs1 = rv[0] * s; s = fmaf(-c2, rs1, s);
          float rs2 = rv[1] * s; s = fmaf(-c2, rs2, s);
          float rs3 = rv[2] * s; s = fmaf(-c2, rs3, s);
          float hh = fmaf(c3, rs0, rs1);
          hh = fmaf(c3, hh, rs2);
          hh = fmaf(c3, hh, rs3);
          i = fmaf(c3p4, i, c2 * hh);
          r0in = rv[3];
          rv = rvn;
        }
        float v = i;
        if (!isfinite(v)) v = 0.0f;
        float x = fmaxf(v, 1e-05f);
        if (x > best) { best = x; bi = t; }
        float lg = __builtin_amdgcn_logf(x) * 0.6931472f;
        if (t > 0) { float d = lg - plg; sd += d; sd2 += d * d; }
        plg = lg;
      }
    }
    __syncthreads();
  }

  // output (si wave, lanes 0-31 only)
  if (wv == GENW + 1 && lane < TRAJ) {
    uint32_t ub = rand_bits32(ku0, ku1, (uint32_t)b);
    float u = __uint_as_float((ub >> 9) | 0x3f800000u) - 1.0f;
    u = fmaxf(0.0f, u);
    float maxat = ((float)bi + u) / 49.0f;
    float mean = sd / 48.0f;
    float var = sd2 / 48.0f - mean * mean;
    float stdv = sqrtf(fmaxf(var, 0.0f));
    out[b * 3 + 0] = (best  - 0.38f) / 0.14f;
    out[b * 3 + 1] = (maxat - 0.21f) / 0.12f;
    out[b * 3 + 2] = (stdv  - 0.14f) / 0.03f;
  }
}

extern "C" void kernel_launch(void* const* d_in, const int* in_sizes, int n_in,
                              void* d_out, int out_size, void* d_ws, size_t ws_size,
                              hipStream_t stream) {
  const float* cond = (const float*)d_in[0];
  const int* seedp = (const int*)d_in[1];
  float* out = (float*)d_out;
  (void)d_ws; (void)ws_size;   // fully LDS-resident: no workspace needed
  fused_kernel<<<NB / TRAJ, 1024, 0, stream>>>(cond, seedp, out);
}

// Round 15
// 150.229 us; speedup vs baseline: 1.0584x; 1.0584x over previous
//
#include <hip/hip_runtime.h>
#include <cstdint>

// XLA emits separate mul/add; contraction off by default. Hot paths use
// explicit fmaf()/hw-transcendentals — measured-safe across 12 rounds
// (absmax pinned at 3.36e7 vs threshold 4.76e34 for r8-r14's variants).
#pragma clang fp contract(off)

#define TSAVES 49
#define SPSAVE 100
#define NB 8192
#define TRAJ 32                    // trajectories per block
#define GENW 14                    // noise-generator waves per block

typedef float f32x4 __attribute__((ext_vector_type(4)));

__device__ __forceinline__ uint32_t rotl32(uint32_t v, int d) {
  return __builtin_rotateleft32(v, (uint32_t)d);
}

// JAX threefry2x32, 20 rounds.
__device__ __forceinline__ void tf2x32(uint32_t k0, uint32_t k1,
                                       uint32_t x0, uint32_t x1,
                                       uint32_t& o0, uint32_t& o1) {
  uint32_t ks2 = k0 ^ k1 ^ 0x1BD11BDAu;
#define TF_ROUND(r) { x0 += x1; x1 = rotl32(x1, r); x1 ^= x0; }
  x0 += k0; x1 += k1;
  TF_ROUND(13) TF_ROUND(15) TF_ROUND(26) TF_ROUND(6)
  x0 += k1; x1 += ks2 + 1u;
  TF_ROUND(17) TF_ROUND(29) TF_ROUND(16) TF_ROUND(24)
  x0 += ks2; x1 += k0 + 2u;
  TF_ROUND(13) TF_ROUND(15) TF_ROUND(26) TF_ROUND(6)
  x0 += k0; x1 += k1 + 3u;
  TF_ROUND(17) TF_ROUND(29) TF_ROUND(16) TF_ROUND(24)
  x0 += k1; x1 += ks2 + 4u;
  TF_ROUND(13) TF_ROUND(15) TF_ROUND(26) TF_ROUND(6)
  x0 += ks2; x1 += k0 + 5u;
#undef TF_ROUND
  o0 = x0; o1 = x1;
}

// jax.random.split(key(seed)), jax_threefry_partitionable=True (fold-like).
__device__ __forceinline__ void derive_keys(int seed, uint32_t& kn0, uint32_t& kn1,
                                            uint32_t& ku0, uint32_t& ku1) {
  uint64_t sv = (uint64_t)(int64_t)seed;
  uint32_t k0 = (uint32_t)(sv >> 32);
  uint32_t k1 = (uint32_t)(sv & 0xffffffffULL);
  tf2x32(k0, k1, 0u, 0u, kn0, kn1);  // keys[0] = k_noise
  tf2x32(k0, k1, 0u, 1u, ku0, ku1);  // keys[1] = k_u
}

// partitionable random_bits(32): counter = (hi=0, lo=n); bits = y0 ^ y1.
__device__ __forceinline__ uint32_t rand_bits32(uint32_t k0, uint32_t k1, uint32_t n) {
  uint32_t y0, y1;
  tf2x32(k0, k1, 0u, n, y0, y1);
  return y0 ^ y1;
}

// bits -> erfinv-core p*u (XLA ErfInv32/Giles). Caller multiplies by
// cpv = (0.1*sqrt(2))*pvol — validated bit-compatible since r8.
__device__ __forceinline__ float bits_to_eu(uint32_t bits) {
#pragma clang fp contract(fast)
  float u01 = __uint_as_float((bits >> 9) | 0x3f800000u) - 1.0f;
  float u = u01 * 2.0f + (-0.99999994f);
  u = fmaxf(-0.99999994f, u);
  float omu2 = 1.0f - u * u;                       // fma(-u,u,1)
  float w = -(__builtin_amdgcn_logf(omu2) * 0.6931472f);  // v_log (log2) * ln2
  float p;
  if (w < 5.0f) {
    float z = w - 2.5f;
    p = 2.81022636e-08f;
    p = 3.43273939e-07f + p * z;
    p = -3.5233877e-06f + p * z;
    p = -4.39150654e-06f + p * z;
    p = 0.00021858087f + p * z;
    p = -0.00125372503f + p * z;
    p = -0.00417768164f + p * z;
    p = 0.246640727f + p * z;
    p = 1.50140941f + p * z;
  } else {
    float z = __builtin_amdgcn_sqrtf(w) - 3.0f;
    p = -0.000200214257f;
    p = 0.000100950558f + p * z;
    p = 0.00134934322f + p * z;
    p = -0.00367342844f + p * z;
    p = 0.00573950773f + p * z;
    p = -0.0076224613f + p * z;
    p = 0.00943887047f + p * z;
    p = 1.00167406f + p * z;
    p = 2.83297682f + p * z;
  }
  return p * u;
}

__device__ __forceinline__ float clip_param(float x) {
  return fminf(0.99999988f, fmaxf(1e-07f, x));
}

// Fused, BARRIER-FREE: 256 blocks x 16 waves. Waves 0..13 generate noise
// into LDS; wave 14 runs the serial r0 chain; wave 15 runs s,i + summarize.
// Round-14 lesson: per-group __syncthreads forced 16-wave lockstep — each
// iteration paid max(stage)+straggler (~8000 cy vs ~5000 ideal) and setprio
// was null. Here each role free-runs, synced by monotone per-wave group
// counters in LDS (volatile spin + s_sleep + threadfence_block acq/rel).
// 2-slot buffers bound producer/consumer skew; dependency DAG is monotone,
// so no deadlock. One __syncthreads total (flag init).
__global__ __launch_bounds__(1024) void fused_kernel(const float* __restrict__ cond,
                                                     const int* __restrict__ seedp,
                                                     float* __restrict__ out) {
  __shared__ f32x4 nbuf[2][25][TRAJ];   // [slot][chunk][traj], 4 steps/chunk, 25.6 KiB
  __shared__ f32x4 rbuf[2][25][TRAJ];   // exiting-r0, same layout, 25.6 KiB
  __shared__ int flags[GENW + 2];       // [0..13]=gen_done, [14]=r0_done, [15]=si_done

  const int tid = threadIdx.x;
  const int lane = tid & 63;
  const int wv = tid >> 6;
  const int bbase = blockIdx.x * TRAJ;
  const int tr = lane & 31;
  const int h = lane >> 5;              // gen: e-parity selector
  const int b = bbase + tr;

  if (tid < GENW + 2) flags[tid] = 0;
  __syncthreads();
  volatile int* vflags = flags;

  uint32_t kn0, kn1, ku0, ku1;
  derive_keys(seedp[0], kn0, kn1, ku0, ku1);

  float pinf = clip_param(cond[b * 4 + 0]);
  float prec = clip_param(cond[b * 4 + 1]);
  float pmr  = clip_param(cond[b * 4 + 2]);
  float pvol = clip_param(cond[b * 4 + 3]);
  const float r0m  = pinf / prec;
  const float dtmr = 0.01f * pmr;
  const float c4 = 1.0f - dtmr;
  const float a4 = dtmr * r0m;
  const float c2 = 0.01f * prec;
  const float c3 = 1.0f - c2;
  const float c3p4 = (c3 * c3) * (c3 * c3);
  const float cpv = 0.14142136f * pvol;     // 0.1*sqrt(2) folded (r8+)

  if (wv < GENW) {
    // -------- producers: noise for groups 0..48 --------
    for (int g = 0; g <= 48; ++g) {
      // reuse nbuf[g&1] (held group g-2): wait r0 finished consuming it
      if (g >= 2) {
        while (vflags[GENW] < g - 1) __builtin_amdgcn_s_sleep(1);
      }
      const uint32_t nbase = (uint32_t)(g * SPSAVE) * (uint32_t)NB + (uint32_t)b;
      float* nb = (float*)&nbuf[g & 1][0][0];
#pragma unroll
      for (int k = 0; k < 4; ++k) {
        const int id = wv + GENW * k;      // 50 chunk-halves over 14 waves
        if (id < 50) {
          const int c = id >> 1;
          const int e = ((id & 1) << 1) | h;
          uint32_t n = nbase + (uint32_t)(4 * c + e) * (uint32_t)NB;
          float eu = bits_to_eu(rand_bits32(kn0, kn1, n));
          nb[(c * 32 + tr) * 4 + e] = eu * cpv;
        }
      }
      __threadfence_block();               // release: drain ds_writes
      if (lane == 0) vflags[wv] = g + 1;
    }
  } else if (wv == GENW) {
    // -------- r0 chain (serial, latency-floor ~34 cy/step) --------
    float r0 = r0m;
    for (int g = 0; g <= 48; ++g) {
      for (;;) {                            // all gen waves done group g?
        int mn = vflags[0];
#pragma unroll
        for (int w = 1; w < GENW; ++w) { int v = vflags[w]; mn = (v < mn) ? v : mn; }
        if (mn >= g + 1) break;
        __builtin_amdgcn_s_sleep(1);
      }
      if (g >= 2) {                         // reuse rbuf[g&1]: si done with g-2?
        while (vflags[GENW + 1] < g - 1) __builtin_amdgcn_s_sleep(1);
      }
      __threadfence_block();                // acquire
      const int src = g & 1;
      f32x4 vd = nbuf[src][0][tr];
#pragma unroll
      for (int c = 0; c < 25; ++c) {
        f32x4 vdn = (c < 24) ? nbuf[src][c + 1][tr] : vd;  // prefetch next
        f32x4 w;
#pragma unroll
        for (int e = 0; e < 4; ++e) {
          float sq  = __builtin_amdgcn_sqrtf(fabsf(r0));
          float r0h = fmaf(c4, r0, a4);
          r0 = fmaf(sq, vd[e], r0h);
          w[e] = r0;                         // exiting r0
        }
        rbuf[src][c][tr] = w;
        vd = vdn;
      }
      __threadfence_block();                // release
      if (lane == 0) vflags[GENW] = g + 1;
    }
  } else {
    // -------- s,i + streaming summarize --------
    float s = 0.99f, i = 0.01f, r0in = r0m;
    float best = -1.0f; int bi = 0;
    float plg = 0.0f, sd = 0.0f, sd2 = 0.0f;
    for (int g = 0; g <= 48; ++g) {
      while (vflags[GENW] < g + 1) __builtin_amdgcn_s_sleep(1);
      __threadfence_block();                // acquire
      const int src = g & 1;
      f32x4 rv = rbuf[src][0][tr];
#pragma unroll
      for (int c = 0; c < 25; ++c) {
        f32x4 rvn = (c < 24) ? rbuf[src][c + 1][tr] : rv;  // prefetch next
        float rs0 = r0in * s;  s = fmaf(-c2, rs0, s);
        float rs1 = rv[0] * s; s = fmaf(-c2, rs1, s);
        float rs2 = rv[1] * s; s = fmaf(-c2, rs2, s);
        float rs3 = rv[2] * s; s = fmaf(-c2, rs3, s);
        float hh = fmaf(c3, rs0, rs1);
        hh = fmaf(c3, hh, rs2);
        hh = fmaf(c3, hh, rs3);
        i = fmaf(c3p4, i, c2 * hh);
        r0in = rv[3];
        rv = rvn;
      }
      float v = i;
      if (!isfinite(v)) v = 0.0f;
      float x = fmaxf(v, 1e-05f);
      if (x > best) { best = x; bi = g; }
      float lg = __builtin_amdgcn_logf(x) * 0.6931472f;
      if (g > 0) { float d = lg - plg; sd += d; sd2 += d * d; }
      plg = lg;
      __threadfence_block();                // release (done reading rbuf[src])
      if (lane == 0) vflags[GENW + 1] = g + 1;
    }
    // output (lanes 0-31)
    if (lane < TRAJ) {
      uint32_t ub = rand_bits32(ku0, ku1, (uint32_t)b);
      float u = __uint_as_float((ub >> 9) | 0x3f800000u) - 1.0f;
      u = fmaxf(0.0f, u);
      float maxat = ((float)bi + u) / 49.0f;
      float mean = sd / 48.0f;
      float var = sd2 / 48.0f - mean * mean;
      float stdv = sqrtf(fmaxf(var, 0.0f));
      out[b * 3 + 0] = (best  - 0.38f) / 0.14f;
      out[b * 3 + 1] = (maxat - 0.21f) / 0.12f;
      out[b * 3 + 2] = (stdv  - 0.14f) / 0.03f;
    }
  }
}

extern "C" void kernel_launch(void* const* d_in, const int* in_sizes, int n_in,
                              void* d_out, int out_size, void* d_ws, size_t ws_size,
                              hipStream_t stream) {
  const float* cond = (const float*)d_in[0];
  const int* seedp = (const int*)d_in[1];
  float* out = (float*)d_out;
  (void)d_ws; (void)ws_size;   // fully LDS-resident: no workspace needed
  fused_kernel<<<NB / TRAJ, 1024, 0, stream>>>(cond, seedp, out);
}

// Round 17
// 142.987 us; speedup vs baseline: 1.1120x; 1.0507x over previous
//
#include <hip/hip_runtime.h>
#include <cstdint>

// XLA emits separate mul/add; contraction off by default. Hot paths use
// explicit fmaf()/hw-transcendentals — measured-safe across 13 rounds
// (absmax pinned at 3.36e7 vs threshold 4.76e34 for r8-r15's variants).
#pragma clang fp contract(off)

#define TSAVES 49
#define SPSAVE 100
#define NB 8192
#define TRAJ 32                    // trajectories per block
#define GENW 14                    // noise-generator waves per block

typedef float f32x4 __attribute__((ext_vector_type(4)));

__device__ __forceinline__ uint32_t rotl32(uint32_t v, int d) {
  return __builtin_rotateleft32(v, (uint32_t)d);
}

// JAX threefry2x32, 20 rounds.
__device__ __forceinline__ void tf2x32(uint32_t k0, uint32_t k1,
                                       uint32_t x0, uint32_t x1,
                                       uint32_t& o0, uint32_t& o1) {
  uint32_t ks2 = k0 ^ k1 ^ 0x1BD11BDAu;
#define TF_ROUND(r) { x0 += x1; x1 = rotl32(x1, r); x1 ^= x0; }
  x0 += k0; x1 += k1;
  TF_ROUND(13) TF_ROUND(15) TF_ROUND(26) TF_ROUND(6)
  x0 += k1; x1 += ks2 + 1u;
  TF_ROUND(17) TF_ROUND(29) TF_ROUND(16) TF_ROUND(24)
  x0 += ks2; x1 += k0 + 2u;
  TF_ROUND(13) TF_ROUND(15) TF_ROUND(26) TF_ROUND(6)
  x0 += k0; x1 += k1 + 3u;
  TF_ROUND(17) TF_ROUND(29) TF_ROUND(16) TF_ROUND(24)
  x0 += k1; x1 += ks2 + 4u;
  TF_ROUND(13) TF_ROUND(15) TF_ROUND(26) TF_ROUND(6)
  x0 += ks2; x1 += k0 + 5u;
#undef TF_ROUND
  o0 = x0; o1 = x1;
}

// jax.random.split(key(seed)), jax_threefry_partitionable=True (fold-like).
__device__ __forceinline__ void derive_keys(int seed, uint32_t& kn0, uint32_t& kn1,
                                            uint32_t& ku0, uint32_t& ku1) {
  uint64_t sv = (uint64_t)(int64_t)seed;
  uint32_t k0 = (uint32_t)(sv >> 32);
  uint32_t k1 = (uint32_t)(sv & 0xffffffffULL);
  tf2x32(k0, k1, 0u, 0u, kn0, kn1);  // keys[0] = k_noise
  tf2x32(k0, k1, 0u, 1u, ku0, ku1);  // keys[1] = k_u
}

// partitionable random_bits(32): counter = (hi=0, lo=n); bits = y0 ^ y1.
__device__ __forceinline__ uint32_t rand_bits32(uint32_t k0, uint32_t k1, uint32_t n) {
  uint32_t y0, y1;
  tf2x32(k0, k1, 0u, n, y0, y1);
  return y0 ^ y1;
}

// bits -> erfinv-core p*u (XLA ErfInv32/Giles). Caller multiplies by
// cpv = (0.1*sqrt(2))*pvol — validated bit-compatible since r8.
__device__ __forceinline__ float bits_to_eu(uint32_t bits) {
#pragma clang fp contract(fast)
  float u01 = __uint_as_float((bits >> 9) | 0x3f800000u) - 1.0f;
  float u = u01 * 2.0f + (-0.99999994f);
  u = fmaxf(-0.99999994f, u);
  float omu2 = 1.0f - u * u;                       // fma(-u,u,1)
  float w = -(__builtin_amdgcn_logf(omu2) * 0.6931472f);  // v_log (log2) * ln2
  float p;
  if (w < 5.0f) {
    float z = w - 2.5f;
    p = 2.81022636e-08f;
    p = 3.43273939e-07f + p * z;
    p = -3.5233877e-06f + p * z;
    p = -4.39150654e-06f + p * z;
    p = 0.00021858087f + p * z;
    p = -0.00125372503f + p * z;
    p = -0.00417768164f + p * z;
    p = 0.246640727f + p * z;
    p = 1.50140941f + p * z;
  } else {
    float z = __builtin_amdgcn_sqrtf(w) - 3.0f;
    p = -0.000200214257f;
    p = 0.000100950558f + p * z;
    p = 0.00134934322f + p * z;
    p = -0.00367342844f + p * z;
    p = 0.00573950773f + p * z;
    p = -0.0076224613f + p * z;
    p = 0.00943887047f + p * z;
    p = 1.00167406f + p * z;
    p = 2.83297682f + p * z;
  }
  return p * u;
}

__device__ __forceinline__ float clip_param(float x) {
  return fminf(0.99999988f, fmaxf(1e-07f, x));
}

// Fused, barrier-free, STATIC schedule (r16's dynamic pool hung; r15's static
// ran — this is r15 + 4-deep nbuf + per-group done-counter):
// 256 blocks x 16 waves. Waves 0..13 generate noise into a 4-deep LDS ring
// (gen runs up to 4 groups ahead — stragglers amortize instead of gating
// every group). Wave 14: serial r0 chain, gated on done[g]==14 (single
// address). Wave 15: s,i + summarize. Monotone counters + s_sleep spins;
// same offset structure r15 validated on HW -> deadlock-free.
__global__ __launch_bounds__(1024) void fused_kernel(const float* __restrict__ cond,
                                                     const int* __restrict__ seedp,
                                                     float* __restrict__ out) {
  __shared__ f32x4 nbuf[4][25][TRAJ];   // 51.2 KiB: 4 noise groups in flight
  __shared__ f32x4 rbuf[2][25][TRAJ];   // 25.6 KiB: exiting-r0, 2 groups
  __shared__ int done[TSAVES];          // gen waves finished with group g (of 14)
  __shared__ int r0cnt, sicnt;

  const int tid = threadIdx.x;
  const int lane = tid & 63;
  const int wv = tid >> 6;
  const int bbase = blockIdx.x * TRAJ;
  const int tr = lane & 31;
  const int h = lane >> 5;              // gen: e-parity selector
  const int b = bbase + tr;

  if (tid < TSAVES) done[tid] = 0;
  if (tid == 0) { r0cnt = 0; sicnt = 0; }
  __syncthreads();

  volatile int* vdone = done;
  volatile int* vr0 = &r0cnt;
  volatile int* vsi = &sicnt;

  uint32_t kn0, kn1, ku0, ku1;
  derive_keys(seedp[0], kn0, kn1, ku0, ku1);

  float pinf = clip_param(cond[b * 4 + 0]);
  float prec = clip_param(cond[b * 4 + 1]);
  float pmr  = clip_param(cond[b * 4 + 2]);
  float pvol = clip_param(cond[b * 4 + 3]);
  const float r0m  = pinf / prec;
  const float dtmr = 0.01f * pmr;
  const float c4 = 1.0f - dtmr;
  const float a4 = dtmr * r0m;
  const float c2 = 0.01f * prec;
  const float c3 = 1.0f - c2;
  const float c3p4 = (c3 * c3) * (c3 * c3);
  const float cpv = 0.14142136f * pvol;     // 0.1*sqrt(2) folded (r8+)

  if (wv < GENW) {
    // -------- producers: static units id = wv + 14k (waves 0-7: 4, 8-13: 3) --------
    for (int g = 0; g <= 48; ++g) {
      if (g >= 4) {                        // slot g&3 free when r0 finished g-4
        while (*vr0 < g - 3) __builtin_amdgcn_s_sleep(1);
      }
      const uint32_t nbase = (uint32_t)(g * SPSAVE) * (uint32_t)NB + (uint32_t)b;
      float* nb = (float*)&nbuf[g & 3][0][0];
#pragma unroll
      for (int k = 0; k < 4; ++k) {
        const int id = wv + GENW * k;      // 50 chunk-halves over 14 waves
        if (id < 50) {
          const int c = id >> 1;
          const int e = ((id & 1) << 1) | h;
          uint32_t n = nbase + (uint32_t)(4 * c + e) * (uint32_t)NB;
          float eu = bits_to_eu(rand_bits32(kn0, kn1, n));
          nb[(c * 32 + tr) * 4 + e] = eu * cpv;
        }
      }
      __threadfence_block();               // drain ds_writes before signaling
      if (lane == 0) atomicAdd(&done[g], 1);
    }
  } else if (wv == GENW) {
    // -------- r0 chain (serial latency floor ~33 cy/step) --------
    float r0 = r0m;
    for (int g = 0; g <= 48; ++g) {
      while (vdone[g] < GENW) __builtin_amdgcn_s_sleep(1);
      if (g >= 2) {                        // rbuf[g&1] reusable when si did g-2
        while (*vsi < g - 1) __builtin_amdgcn_s_sleep(1);
      }
      __threadfence_block();               // acquire
      const int sn = g & 3, sr = g & 1;
      f32x4 vd = nbuf[sn][0][tr];
#pragma unroll
      for (int c = 0; c < 25; ++c) {
        f32x4 vdn = (c < 24) ? nbuf[sn][c + 1][tr] : vd;  // prefetch next
        f32x4 w;
#pragma unroll
        for (int e = 0; e < 4; ++e) {
          float sq  = __builtin_amdgcn_sqrtf(fabsf(r0));
          float r0h = fmaf(c4, r0, a4);
          r0 = fmaf(sq, vd[e], r0h);
          w[e] = r0;                        // exiting r0
        }
        rbuf[sr][c][tr] = w;
        vd = vdn;
      }
      __threadfence_block();               // release
      if (lane == 0) *vr0 = g + 1;
    }
  } else {
    // -------- s,i + streaming summarize --------
    float s = 0.99f, i = 0.01f, r0in = r0m;
    float best = -1.0f; int bi = 0;
    float plg = 0.0f, sd = 0.0f, sd2 = 0.0f;
    for (int g = 0; g <= 48; ++g) {
      while (*vr0 < g + 1) __builtin_amdgcn_s_sleep(1);
      __threadfence_block();               // acquire
      const int sr = g & 1;
      f32x4 rv = rbuf[sr][0][tr];
#pragma unroll
      for (int c = 0; c < 25; ++c) {
        f32x4 rvn = (c < 24) ? rbuf[sr][c + 1][tr] : rv;  // prefetch next
        float rs0 = r0in * s;  s = fmaf(-c2, rs0, s);
        float rs1 = rv[0] * s; s = fmaf(-c2, rs1, s);
        float rs2 = rv[1] * s; s = fmaf(-c2, rs2, s);
        float rs3 = rv[2] * s; s = fmaf(-c2, rs3, s);
        float hh = fmaf(c3, rs0, rs1);
        hh = fmaf(c3, hh, rs2);
        hh = fmaf(c3, hh, rs3);
        i = fmaf(c3p4, i, c2 * hh);
        r0in = rv[3];
        rv = rvn;
      }
      float v = i;
      if (!isfinite(v)) v = 0.0f;
      float x = fmaxf(v, 1e-05f);
      if (x > best) { best = x; bi = g; }
      float lg = __builtin_amdgcn_logf(x) * 0.6931472f;
      if (g > 0) { float d = lg - plg; sd += d; sd2 += d * d; }
      plg = lg;
      __threadfence_block();               // release (done reading rbuf[sr])
      if (lane == 0) *vsi = g + 1;
    }
    if (lane < TRAJ) {
      uint32_t ub = rand_bits32(ku0, ku1, (uint32_t)b);
      float u = __uint_as_float((ub >> 9) | 0x3f800000u) - 1.0f;
      u = fmaxf(0.0f, u);
      float maxat = ((float)bi + u) / 49.0f;
      float mean = sd / 48.0f;
      float var = sd2 / 48.0f - mean * mean;
      float stdv = sqrtf(fmaxf(var, 0.0f));
      out[b * 3 + 0] = (best  - 0.38f) / 0.14f;
      out[b * 3 + 1] = (maxat - 0.21f) / 0.12f;
      out[b * 3 + 2] = (stdv  - 0.14f) / 0.03f;
    }
  }
}

extern "C" void kernel_launch(void* const* d_in, const int* in_sizes, int n_in,
                              void* d_out, int out_size, void* d_ws, size_t ws_size,
                              hipStream_t stream) {
  const float* cond = (const float*)d_in[0];
  const int* seedp = (const int*)d_in[1];
  float* out = (float*)d_out;
  (void)d_ws; (void)ws_size;   // fully LDS-resident: no workspace needed
  fused_kernel<<<NB / TRAJ, 1024, 0, stream>>>(cond, seedp, out);
}

// Round 18
// 142.843 us; speedup vs baseline: 1.1131x; 1.0010x over previous
//
#include <hip/hip_runtime.h>
#include <cstdint>

// XLA emits separate mul/add; contraction off by default. Hot paths use
// explicit fmaf()/hw-transcendentals — measured-safe across 14 rounds
// (absmax pinned at 3.36e7 vs threshold 4.76e34 for r8-r17's variants).
#pragma clang fp contract(off)

#define TSAVES 49
#define SPSAVE 100
#define NB 8192
#define TRAJ 32                    // trajectories per block
#define GENW 14                    // noise-generator waves per block

typedef float f32x4 __attribute__((ext_vector_type(4)));

__device__ __forceinline__ uint32_t rotl32(uint32_t v, int d) {
  return __builtin_rotateleft32(v, (uint32_t)d);
}

// JAX threefry2x32, 20 rounds.
__device__ __forceinline__ void tf2x32(uint32_t k0, uint32_t k1,
                                       uint32_t x0, uint32_t x1,
                                       uint32_t& o0, uint32_t& o1) {
  uint32_t ks2 = k0 ^ k1 ^ 0x1BD11BDAu;
#define TF_ROUND(r) { x0 += x1; x1 = rotl32(x1, r); x1 ^= x0; }
  x0 += k0; x1 += k1;
  TF_ROUND(13) TF_ROUND(15) TF_ROUND(26) TF_ROUND(6)
  x0 += k1; x1 += ks2 + 1u;
  TF_ROUND(17) TF_ROUND(29) TF_ROUND(16) TF_ROUND(24)
  x0 += ks2; x1 += k0 + 2u;
  TF_ROUND(13) TF_ROUND(15) TF_ROUND(26) TF_ROUND(6)
  x0 += k0; x1 += k1 + 3u;
  TF_ROUND(17) TF_ROUND(29) TF_ROUND(16) TF_ROUND(24)
  x0 += k1; x1 += ks2 + 4u;
  TF_ROUND(13) TF_ROUND(15) TF_ROUND(26) TF_ROUND(6)
  x0 += ks2; x1 += k0 + 5u;
#undef TF_ROUND
  o0 = x0; o1 = x1;
}

// jax.random.split(key(seed)), jax_threefry_partitionable=True (fold-like).
__device__ __forceinline__ void derive_keys(int seed, uint32_t& kn0, uint32_t& kn1,
                                            uint32_t& ku0, uint32_t& ku1) {
  uint64_t sv = (uint64_t)(int64_t)seed;
  uint32_t k0 = (uint32_t)(sv >> 32);
  uint32_t k1 = (uint32_t)(sv & 0xffffffffULL);
  tf2x32(k0, k1, 0u, 0u, kn0, kn1);  // keys[0] = k_noise
  tf2x32(k0, k1, 0u, 1u, ku0, ku1);  // keys[1] = k_u
}

// partitionable random_bits(32): counter = (hi=0, lo=n); bits = y0 ^ y1.
__device__ __forceinline__ uint32_t rand_bits32(uint32_t k0, uint32_t k1, uint32_t n) {
  uint32_t y0, y1;
  tf2x32(k0, k1, 0u, n, y0, y1);
  return y0 ^ y1;
}

// bits -> erfinv-core p*u (XLA ErfInv32/Giles). Caller multiplies by
// cpv = (0.1*sqrt(2))*pvol — validated bit-compatible since r8.
__device__ __forceinline__ float bits_to_eu(uint32_t bits) {
#pragma clang fp contract(fast)
  float u01 = __uint_as_float((bits >> 9) | 0x3f800000u) - 1.0f;
  float u = u01 * 2.0f + (-0.99999994f);
  u = fmaxf(-0.99999994f, u);
  float omu2 = 1.0f - u * u;                       // fma(-u,u,1)
  float w = -(__builtin_amdgcn_logf(omu2) * 0.6931472f);  // v_log (log2) * ln2
  float p;
  if (w < 5.0f) {
    float z = w - 2.5f;
    p = 2.81022636e-08f;
    p = 3.43273939e-07f + p * z;
    p = -3.5233877e-06f + p * z;
    p = -4.39150654e-06f + p * z;
    p = 0.00021858087f + p * z;
    p = -0.00125372503f + p * z;
    p = -0.00417768164f + p * z;
    p = 0.246640727f + p * z;
    p = 1.50140941f + p * z;
  } else {
    float z = __builtin_amdgcn_sqrtf(w) - 3.0f;
    p = -0.000200214257f;
    p = 0.000100950558f + p * z;
    p = 0.00134934322f + p * z;
    p = -0.00367342844f + p * z;
    p = 0.00573950773f + p * z;
    p = -0.0076224613f + p * z;
    p = 0.00943887047f + p * z;
    p = 1.00167406f + p * z;
    p = 2.83297682f + p * z;
  }
  return p * u;
}

__device__ __forceinline__ float clip_param(float x) {
  return fminf(0.99999988f, fmaxf(1e-07f, x));
}

// Fused, barrier-free, static schedule (r17) + s_setprio(1) on sim waves.
// r14's setprio null was measured in the LOCKSTEP version (wrong regime —
// barrier dominated). Here waves free-run with persistent role-split: the
// serial r0 chain's dependent instr must beat 3 always-ready gen waves on
// its SIMD (measured ~2x chain slowdown in-situ, r13/r17); priority hands
// it the slot the cycle its dep resolves. Spins s_sleep, so no starvation.
__global__ __launch_bounds__(1024) void fused_kernel(const float* __restrict__ cond,
                                                     const int* __restrict__ seedp,
                                                     float* __restrict__ out) {
  __shared__ f32x4 nbuf[4][25][TRAJ];   // 51.2 KiB: 4 noise groups in flight
  __shared__ f32x4 rbuf[2][25][TRAJ];   // 25.6 KiB: exiting-r0, 2 groups
  __shared__ int done[TSAVES];          // gen waves finished with group g (of 14)
  __shared__ int r0cnt, sicnt;

  const int tid = threadIdx.x;
  const int lane = tid & 63;
  const int wv = tid >> 6;
  const int bbase = blockIdx.x * TRAJ;
  const int tr = lane & 31;
  const int h = lane >> 5;              // gen: e-parity selector
  const int b = bbase + tr;

  if (tid < TSAVES) done[tid] = 0;
  if (tid == 0) { r0cnt = 0; sicnt = 0; }
  __syncthreads();

  volatile int* vdone = done;
  volatile int* vr0 = &r0cnt;
  volatile int* vsi = &sicnt;

  if (wv >= GENW) __builtin_amdgcn_s_setprio(1);   // sim waves win arbitration

  uint32_t kn0, kn1, ku0, ku1;
  derive_keys(seedp[0], kn0, kn1, ku0, ku1);

  float pinf = clip_param(cond[b * 4 + 0]);
  float prec = clip_param(cond[b * 4 + 1]);
  float pmr  = clip_param(cond[b * 4 + 2]);
  float pvol = clip_param(cond[b * 4 + 3]);
  const float r0m  = pinf / prec;
  const float dtmr = 0.01f * pmr;
  const float c4 = 1.0f - dtmr;
  const float a4 = dtmr * r0m;
  const float c2 = 0.01f * prec;
  const float c3 = 1.0f - c2;
  const float c3p4 = (c3 * c3) * (c3 * c3);
  const float cpv = 0.14142136f * pvol;     // 0.1*sqrt(2) folded (r8+)

  if (wv < GENW) {
    // -------- producers: static units id = wv + 14k (waves 0-7: 4, 8-13: 3) --------
    for (int g = 0; g <= 48; ++g) {
      if (g >= 4) {                        // slot g&3 free when r0 finished g-4
        while (*vr0 < g - 3) __builtin_amdgcn_s_sleep(1);
      }
      const uint32_t nbase = (uint32_t)(g * SPSAVE) * (uint32_t)NB + (uint32_t)b;
      float* nb = (float*)&nbuf[g & 3][0][0];
#pragma unroll
      for (int k = 0; k < 4; ++k) {
        const int id = wv + GENW * k;      // 50 chunk-halves over 14 waves
        if (id < 50) {
          const int c = id >> 1;
          const int e = ((id & 1) << 1) | h;
          uint32_t n = nbase + (uint32_t)(4 * c + e) * (uint32_t)NB;
          float eu = bits_to_eu(rand_bits32(kn0, kn1, n));
          nb[(c * 32 + tr) * 4 + e] = eu * cpv;
        }
      }
      __threadfence_block();               // drain ds_writes before signaling
      if (lane == 0) atomicAdd(&done[g], 1);
    }
  } else if (wv == GENW) {
    // -------- r0 chain (serial latency floor) --------
    float r0 = r0m;
    for (int g = 0; g <= 48; ++g) {
      while (vdone[g] < GENW) __builtin_amdgcn_s_sleep(1);
      if (g >= 2) {                        // rbuf[g&1] reusable when si did g-2
        while (*vsi < g - 1) __builtin_amdgcn_s_sleep(1);
      }
      __threadfence_block();               // acquire
      const int sn = g & 3, sr = g & 1;
      f32x4 vd = nbuf[sn][0][tr];
#pragma unroll
      for (int c = 0; c < 25; ++c) {
        f32x4 vdn = (c < 24) ? nbuf[sn][c + 1][tr] : vd;  // prefetch next
        f32x4 w;
#pragma unroll
        for (int e = 0; e < 4; ++e) {
          float sq  = __builtin_amdgcn_sqrtf(fabsf(r0));
          float r0h = fmaf(c4, r0, a4);
          r0 = fmaf(sq, vd[e], r0h);
          w[e] = r0;                        // exiting r0
        }
        rbuf[sr][c][tr] = w;
        vd = vdn;
      }
      __threadfence_block();               // release
      if (lane == 0) *vr0 = g + 1;
    }
  } else {
    // -------- s,i + streaming summarize --------
    float s = 0.99f, i = 0.01f, r0in = r0m;
    float best = -1.0f; int bi = 0;
    float plg = 0.0f, sd = 0.0f, sd2 = 0.0f;
    for (int g = 0; g <= 48; ++g) {
      while (*vr0 < g + 1) __builtin_amdgcn_s_sleep(1);
      __threadfence_block();               // acquire
      const int sr = g & 1;
      f32x4 rv = rbuf[sr][0][tr];
#pragma unroll
      for (int c = 0; c < 25; ++c) {
        f32x4 rvn = (c < 24) ? rbuf[sr][c + 1][tr] : rv;  // prefetch next
        float rs0 = r0in * s;  s = fmaf(-c2, rs0, s);
        float rs1 = rv[0] * s; s = fmaf(-c2, rs1, s);
        float rs2 = rv[1] * s; s = fmaf(-c2, rs2, s);
        float rs3 = rv[2] * s; s = fmaf(-c2, rs3, s);
        float hh = fmaf(c3, rs0, rs1);
        hh = fmaf(c3, hh, rs2);
        hh = fmaf(c3, hh, rs3);
        i = fmaf(c3p4, i, c2 * hh);
        r0in = rv[3];
        rv = rvn;
      }
      float v = i;
      if (!isfinite(v)) v = 0.0f;
      float x = fmaxf(v, 1e-05f);
      if (x > best) { best = x; bi = g; }
      float lg = __builtin_amdgcn_logf(x) * 0.6931472f;
      if (g > 0) { float d = lg - plg; sd += d; sd2 += d * d; }
      plg = lg;
      __threadfence_block();               // release (done reading rbuf[sr])
      if (lane == 0) *vsi = g + 1;
    }
    if (lane < TRAJ) {
      uint32_t ub = rand_bits32(ku0, ku1, (uint32_t)b);
      float u = __uint_as_float((ub >> 9) | 0x3f800000u) - 1.0f;
      u = fmaxf(0.0f, u);
      float maxat = ((float)bi + u) / 49.0f;
      float mean = sd / 48.0f;
      float var = sd2 / 48.0f - mean * mean;
      float stdv = sqrtf(fmaxf(var, 0.0f));
      out[b * 3 + 0] = (best  - 0.38f) / 0.14f;
      out[b * 3 + 1] = (maxat - 0.21f) / 0.12f;
      out[b * 3 + 2] = (stdv  - 0.14f) / 0.03f;
    }
  }
}

extern "C" void kernel_launch(void* const* d_in, const int* in_sizes, int n_in,
                              void* d_out, int out_size, void* d_ws, size_t ws_size,
                              hipStream_t stream) {
  const float* cond = (const float*)d_in[0];
  const int* seedp = (const int*)d_in[1];
  float* out = (float*)d_out;
  (void)d_ws; (void)ws_size;   // fully LDS-resident: no workspace needed
  fused_kernel<<<NB / TRAJ, 1024, 0, stream>>>(cond, seedp, out);
}

// Round 19
// 131.267 us; speedup vs baseline: 1.2113x; 1.0882x over previous
//
#include <hip/hip_runtime.h>
#include <cstdint>

// XLA emits separate mul/add; contraction off by default. Hot paths use
// explicit fmaf()/hw-transcendentals — measured-safe across 15 rounds
// (absmax pinned at 3.36e7 vs threshold 4.76e34 for r8-r18's variants).
#pragma clang fp contract(off)

#define TSAVES 49
#define SPSAVE 100
#define NB 8192
#define TRAJ 32                    // trajectories per block
#define GENW 14                    // noise-generator waves per block
#define NDEPTH 6                   // noise ring depth (gen run-ahead)

// Per-wave gen-unit counts, nibble-packed, w0 in low nibble. SIMD s hosts
// waves {s, s+4, s+8, s+12}: SIMD0 {0,4,8,12}=4+4+4+3=15, SIMD1 {1,5,9,13}=15,
// SIMD2 {2,6,10}=3+2+2=7 (+r0 chain wave 14), SIMD3 {3,7,11}=5+4+4=13 (+si).
// Rebalanced so the serial r0 chain's SIMD is nearly gen-free (r18 analysis:
// chain ran ~2x slower co-resident with 3 busy gen waves; setprio null).
#define CNTPACK 0x33424442445344ULL

typedef float f32x4 __attribute__((ext_vector_type(4)));

__device__ __forceinline__ uint32_t rotl32(uint32_t v, int d) {
  return __builtin_rotateleft32(v, (uint32_t)d);
}

// JAX threefry2x32, 20 rounds.
__device__ __forceinline__ void tf2x32(uint32_t k0, uint32_t k1,
                                       uint32_t x0, uint32_t x1,
                                       uint32_t& o0, uint32_t& o1) {
  uint32_t ks2 = k0 ^ k1 ^ 0x1BD11BDAu;
#define TF_ROUND(r) { x0 += x1; x1 = rotl32(x1, r); x1 ^= x0; }
  x0 += k0; x1 += k1;
  TF_ROUND(13) TF_ROUND(15) TF_ROUND(26) TF_ROUND(6)
  x0 += k1; x1 += ks2 + 1u;
  TF_ROUND(17) TF_ROUND(29) TF_ROUND(16) TF_ROUND(24)
  x0 += ks2; x1 += k0 + 2u;
  TF_ROUND(13) TF_ROUND(15) TF_ROUND(26) TF_ROUND(6)
  x0 += k0; x1 += k1 + 3u;
  TF_ROUND(17) TF_ROUND(29) TF_ROUND(16) TF_ROUND(24)
  x0 += k1; x1 += ks2 + 4u;
  TF_ROUND(13) TF_ROUND(15) TF_ROUND(26) TF_ROUND(6)
  x0 += ks2; x1 += k0 + 5u;
#undef TF_ROUND
  o0 = x0; o1 = x1;
}

// jax.random.split(key(seed)), jax_threefry_partitionable=True (fold-like).
__device__ __forceinline__ void derive_keys(int seed, uint32_t& kn0, uint32_t& kn1,
                                            uint32_t& ku0, uint32_t& ku1) {
  uint64_t sv = (uint64_t)(int64_t)seed;
  uint32_t k0 = (uint32_t)(sv >> 32);
  uint32_t k1 = (uint32_t)(sv & 0xffffffffULL);
  tf2x32(k0, k1, 0u, 0u, kn0, kn1);  // keys[0] = k_noise
  tf2x32(k0, k1, 0u, 1u, ku0, ku1);  // keys[1] = k_u
}

// partitionable random_bits(32): counter = (hi=0, lo=n); bits = y0 ^ y1.
__device__ __forceinline__ uint32_t rand_bits32(uint32_t k0, uint32_t k1, uint32_t n) {
  uint32_t y0, y1;
  tf2x32(k0, k1, 0u, n, y0, y1);
  return y0 ^ y1;
}

// bits -> erfinv-core p*u (XLA ErfInv32/Giles). Caller multiplies by
// cpv = (0.1*sqrt(2))*pvol — validated bit-compatible since r8.
__device__ __forceinline__ float bits_to_eu(uint32_t bits) {
#pragma clang fp contract(fast)
  float u01 = __uint_as_float((bits >> 9) | 0x3f800000u) - 1.0f;
  float u = u01 * 2.0f + (-0.99999994f);
  u = fmaxf(-0.99999994f, u);
  float omu2 = 1.0f - u * u;                       // fma(-u,u,1)
  float w = -(__builtin_amdgcn_logf(omu2) * 0.6931472f);  // v_log (log2) * ln2
  float p;
  if (w < 5.0f) {
    float z = w - 2.5f;
    p = 2.81022636e-08f;
    p = 3.43273939e-07f + p * z;
    p = -3.5233877e-06f + p * z;
    p = -4.39150654e-06f + p * z;
    p = 0.00021858087f + p * z;
    p = -0.00125372503f + p * z;
    p = -0.00417768164f + p * z;
    p = 0.246640727f + p * z;
    p = 1.50140941f + p * z;
  } else {
    float z = __builtin_amdgcn_sqrtf(w) - 3.0f;
    p = -0.000200214257f;
    p = 0.000100950558f + p * z;
    p = 0.00134934322f + p * z;
    p = -0.00367342844f + p * z;
    p = 0.00573950773f + p * z;
    p = -0.0076224613f + p * z;
    p = 0.00943887047f + p * z;
    p = 1.00167406f + p * z;
    p = 2.83297682f + p * z;
  }
  return p * u;
}

__device__ __forceinline__ float clip_param(float x) {
  return fminf(0.99999988f, fmaxf(1e-07f, x));
}

// Fused, barrier-free, static schedule, SIMD-rebalanced (see CNTPACK note).
// 256 blocks x 16 waves. Gen waves 0..13 fill a 6-deep LDS noise ring;
// wave 14 runs the serial r0 chain; wave 15 runs s,i + summarize.
// Monotone counters + s_sleep spins (r15/r17-validated structure).
__global__ __launch_bounds__(1024) void fused_kernel(const float* __restrict__ cond,
                                                     const int* __restrict__ seedp,
                                                     float* __restrict__ out) {
  __shared__ f32x4 nbuf[NDEPTH][25][TRAJ];  // 76.8 KiB: noise ring
  __shared__ f32x4 rbuf[2][25][TRAJ];       // 25.6 KiB: exiting-r0, 2 groups
  __shared__ int done[TSAVES];              // gen waves finished with group g (of 14)
  __shared__ int r0cnt, sicnt;

  const int tid = threadIdx.x;
  const int lane = tid & 63;
  const int wv = tid >> 6;
  const int bbase = blockIdx.x * TRAJ;
  const int tr = lane & 31;
  const int h = lane >> 5;              // gen: e-parity selector
  const int b = bbase + tr;

  if (tid < TSAVES) done[tid] = 0;
  if (tid == 0) { r0cnt = 0; sicnt = 0; }
  __syncthreads();

  volatile int* vdone = done;
  volatile int* vr0 = &r0cnt;
  volatile int* vsi = &sicnt;

  uint32_t kn0, kn1, ku0, ku1;
  derive_keys(seedp[0], kn0, kn1, ku0, ku1);

  float pinf = clip_param(cond[b * 4 + 0]);
  float prec = clip_param(cond[b * 4 + 1]);
  float pmr  = clip_param(cond[b * 4 + 2]);
  float pvol = clip_param(cond[b * 4 + 3]);
  const float r0m  = pinf / prec;
  const float dtmr = 0.01f * pmr;
  const float c4 = 1.0f - dtmr;
  const float a4 = dtmr * r0m;
  const float c2 = 0.01f * prec;
  const float c3 = 1.0f - c2;
  const float c3p4 = (c3 * c3) * (c3 * c3);
  const float cpv = 0.14142136f * pvol;     // 0.1*sqrt(2) folded (r8+)

  if (wv < GENW) {
    // -------- producers: rebalanced static units --------
    const int cnt = (int)((CNTPACK >> (4 * wv)) & 0xFULL);
    int off = 0;
#pragma unroll
    for (int w = 0; w < GENW; ++w) if (w < wv) off += (int)((CNTPACK >> (4 * w)) & 0xFULL);
    for (int g = 0; g <= 48; ++g) {
      if (g >= NDEPTH) {                   // ring slot free when r0 did g-NDEPTH
        while (*vr0 < g - (NDEPTH - 1)) __builtin_amdgcn_s_sleep(1);
      }
      const uint32_t nbase = (uint32_t)(g * SPSAVE) * (uint32_t)NB + (uint32_t)b;
      float* nb = (float*)&nbuf[g % NDEPTH][0][0];
      for (int k = 0; k < cnt; ++k) {
        const int id = off + k;            // 0..49
        const int c = id >> 1;
        const int e = ((id & 1) << 1) | h;
        uint32_t n = nbase + (uint32_t)(4 * c + e) * (uint32_t)NB;
        float eu = bits_to_eu(rand_bits32(kn0, kn1, n));
        nb[(c * 32 + tr) * 4 + e] = eu * cpv;
      }
      __threadfence_block();               // drain ds_writes before signaling
      if (lane == 0) atomicAdd(&done[g], 1);
    }
  } else if (wv == GENW) {
    // -------- r0 chain (serial latency floor; near-clean SIMD now) --------
    float r0 = r0m;
    for (int g = 0; g <= 48; ++g) {
      while (vdone[g] < GENW) __builtin_amdgcn_s_sleep(1);
      if (g >= 2) {                        // rbuf[g&1] reusable when si did g-2
        while (*vsi < g - 1) __builtin_amdgcn_s_sleep(1);
      }
      __threadfence_block();               // acquire
      const int sn = g % NDEPTH, sr = g & 1;
      f32x4 vd = nbuf[sn][0][tr];
#pragma unroll
      for (int c = 0; c < 25; ++c) {
        f32x4 vdn = (c < 24) ? nbuf[sn][c + 1][tr] : vd;  // prefetch next
        f32x4 w;
#pragma unroll
        for (int e = 0; e < 4; ++e) {
          float sq  = __builtin_amdgcn_sqrtf(fabsf(r0));
          float r0h = fmaf(c4, r0, a4);
          r0 = fmaf(sq, vd[e], r0h);
          w[e] = r0;                        // exiting r0
        }
        rbuf[sr][c][tr] = w;
        vd = vdn;
      }
      __threadfence_block();               // release
      if (lane == 0) *vr0 = g + 1;
    }
  } else {
    // -------- s,i + streaming summarize --------
    float s = 0.99f, i = 0.01f, r0in = r0m;
    float best = -1.0f; int bi = 0;
    float plg = 0.0f, sd = 0.0f, sd2 = 0.0f;
    for (int g = 0; g <= 48; ++g) {
      while (*vr0 < g + 1) __builtin_amdgcn_s_sleep(1);
      __threadfence_block();               // acquire
      const int sr = g & 1;
      f32x4 rv = rbuf[sr][0][tr];
#pragma unroll
      for (int c = 0; c < 25; ++c) {
        f32x4 rvn = (c < 24) ? rbuf[sr][c + 1][tr] : rv;  // prefetch next
        float rs0 = r0in * s;  s = fmaf(-c2, rs0, s);
        float rs1 = rv[0] * s; s = fmaf(-c2, rs1, s);
        float rs2 = rv[1] * s; s = fmaf(-c2, rs2, s);
        float rs3 = rv[2] * s; s = fmaf(-c2, rs3, s);
        float hh = fmaf(c3, rs0, rs1);
        hh = fmaf(c3, hh, rs2);
        hh = fmaf(c3, hh, rs3);
        i = fmaf(c3p4, i, c2 * hh);
        r0in = rv[3];
        rv = rvn;
      }
      float v = i;
      if (!isfinite(v)) v = 0.0f;
      float x = fmaxf(v, 1e-05f);
      if (x > best) { best = x; bi = g; }
      float lg = __builtin_amdgcn_logf(x) * 0.6931472f;
      if (g > 0) { float d = lg - plg; sd += d; sd2 += d * d; }
      plg = lg;
      __threadfence_block();               // release (done reading rbuf[sr])
      if (lane == 0) *vsi = g + 1;
    }
    if (lane < TRAJ) {
      uint32_t ub = rand_bits32(ku0, ku1, (uint32_t)b);
      float u = __uint_as_float((ub >> 9) | 0x3f800000u) - 1.0f;
      u = fmaxf(0.0f, u);
      float maxat = ((float)bi + u) / 49.0f;
      float mean = sd / 48.0f;
      float var = sd2 / 48.0f - mean * mean;
      float stdv = sqrtf(fmaxf(var, 0.0f));
      out[b * 3 + 0] = (best  - 0.38f) / 0.14f;
      out[b * 3 + 1] = (maxat - 0.21f) / 0.12f;
      out[b * 3 + 2] = (stdv  - 0.14f) / 0.03f;
    }
  }
}

extern "C" void kernel_launch(void* const* d_in, const int* in_sizes, int n_in,
                              void* d_out, int out_size, void* d_ws, size_t ws_size,
                              hipStream_t stream) {
  const float* cond = (const float*)d_in[0];
  const int* seedp = (const int*)d_in[1];
  float* out = (float*)d_out;
  (void)d_ws; (void)ws_size;   // fully LDS-resident: no workspace needed
  fused_kernel<<<NB / TRAJ, 1024, 0, stream>>>(cond, seedp, out);
}